// Round 15
// baseline (424.870 us; speedup 1.0000x reference)
//
#include <hip/hip_runtime.h>
#include <cstdint>
#include <cstddef>

#define B_ 16
#define NROW 1024      // E == N == 1024
#define H_ 128
#define NW 16          // u64 words per 1024-bit adjacency row

typedef unsigned short u16;
typedef unsigned long long u64;
typedef __attribute__((ext_vector_type(8))) short short8;   // 8 bf16 (4 VGPRs)
typedef __attribute__((ext_vector_type(4))) float f32x4;    // MFMA C/D

__device__ __forceinline__ u16 f2bf(float f) {   // RTNE float->bf16
    unsigned u = __float_as_uint(f);
    return (u16)((u + 0x7fffu + ((u >> 16) & 1u)) >> 16);
}
__device__ __forceinline__ float bf2f(u16 h) {
    return __uint_as_float((unsigned)h << 16);
}

// --- adj (B,E,N) f32 -> bit matrix (B*E rows x 16 u64 words) ---
__global__ void adj_to_bits(const float* __restrict__ adj, u64* __restrict__ bits) {
    int be = blockIdx.x;                      // 16384
    const float* row = adj + (size_t)be * NROW;
    int tid = threadIdx.x, lane = tid & 63, wv = tid >> 6;
    for (int c0 = 0; c0 < NROW; c0 += 256) {
        float v = row[c0 + tid];
        u64 m = __ballot(v != 0.0f);
        if (lane == 0) bits[(size_t)be * NW + (c0 >> 6) + wv] = m;
    }
}

// --- fp32 -> bf16 copy (row-major), 4 elems/thread ---
__global__ void to_bf16(const float* __restrict__ in, u16* __restrict__ out) {
    int i = blockIdx.x * 256 + threadIdx.x;
    float4 v = ((const float4*)in)[i];
    ushort4 r;
    r.x = f2bf(v.x); r.y = f2bf(v.y); r.z = f2bf(v.z); r.w = f2bf(v.w);
    ((ushort4*)out)[i] = r;
}

// --- vt[b][d][n] = bf16(src[b][n][d]), d<128 ---
__global__ void trans_vt(const float* __restrict__ src, u16* __restrict__ vt) {
    int blk = blockIdx.x;                 // B_*128
    int b = blk >> 7, d = blk & 127;
    int t = threadIdx.x;                  // 256 threads x 4 n each
    const float* sp = src + ((size_t)b << 10) * H_ + d;
    ushort4 o;
    o.x = f2bf(sp[(size_t)(t * 4 + 0) * H_]);
    o.y = f2bf(sp[(size_t)(t * 4 + 1) * H_]);
    o.z = f2bf(sp[(size_t)(t * 4 + 2) * H_]);
    o.w = f2bf(sp[(size_t)(t * 4 + 3) * H_]);
    ((ushort4*)(vt + ((size_t)b * H_ + d) * NROW))[t] = o;
}

// --- qs[b][r][k] = bf16(src[b][r][k] * w[k] * log2e) ---
__global__ void prep_q(const float* __restrict__ src, const float* __restrict__ w,
                       u16* __restrict__ qs) {
    int idx = blockIdx.x * 256 + threadIdx.x;   // float4 index
    float4 v = ((const float4*)src)[idx];
    float4 wv = ((const float4*)w)[idx & 31];
    const float L2E = 1.44269504f;
    ushort4 r;
    r.x = f2bf(v.x * wv.x * L2E);
    r.y = f2bf(v.y * wv.y * L2E);
    r.z = f2bf(v.z * wv.z * L2E);
    r.w = f2bf(v.w * wv.w * L2E);
    ((ushort4*)qs)[idx] = r;
}

// --- Fused flash attention phase, M-tile 16 (high-occupancy form) ---
// Grid 1024 = 16 b x 64 mt; 512 thr = 8 waves; LDS 8.5 KB -> 3-4 blocks/CU.
// KV and VT fragments load DIRECTLY from global (L2): within a block each
// element feeds exactly one wave (waves own disjoint n-/d-col slabs), so LDS
// staging of B-operands is pure overhead. Only the q-tile (reused 8x across
// nt) and the P tile (cross-wave k-sharing in PV) live in LDS.
// Per nt (8 iters): S = Qs.KV^T (4 MFMA) -> mask/leaky/exp2 -> P bf16 to
// swizzled LDS (+ bf16-rounded fp32 denom) -> barrier -> O += P.VT^T
// (4 MFMA, VT frags from global) -> barrier.
// MODE=1 (edge_init): P = mask bits as {0,1} (skips Qs/KV/S).
// TM=0: mask=bits[m-row][n-col] (alpha). TM=1: mask=bits[n-col][m-row] (beta).
// aux=1: also write bf16 row-major copy + VT-layout copy of the output.
// MFMA fragment mappings identical to r13/r14-validated kernels.
__global__ void __launch_bounds__(512, 6)
fused_attn(const u16* __restrict__ qs, const u16* __restrict__ kvbf,
           const u16* __restrict__ vt, const u64* __restrict__ bits,
           const float* __restrict__ w,
           float* __restrict__ outf, u16* __restrict__ bfo, u16* __restrict__ vto,
           int TM, int MODE, int aux) {
    __shared__ uint4 Al[16 * 16];     // 4 KB  q tile [16 m][128 k]
    __shared__ uint4 Pl[16 * 16];     // 4 KB  P tile [16 m][128 n]
    __shared__ float dLds[8 * 16];    // 512 B per-wave row denominators

    int x = blockIdx.x;               // 1024
    int xcd = x & 7;
    int j = x >> 3;                   // 0..127
    int b = xcd + ((j >> 6) << 3);    // batches {xcd, xcd+8} on XCD xcd
    int mt = j & 63;
    int t = threadIdx.x;
    int lane = t & 63, wv = t >> 6;   // 8 waves
    int r15 = lane & 15, g = lane >> 4;

    if (MODE == 0 && t < 256) {
        int row = t >> 4, kc = t & 15;
        Al[row * 16 + (kc ^ (row & 7))] =
            ((const uint4*)qs)[((size_t)(b << 10) + mt * 16 + row) * 16 + kc];
    }
    float wb = (MODE == 0) ? w[H_] * 1.44269504f : 0.f;
    f32x4 oacc = {};
    float dsum[4] = {};
    __syncthreads();

    for (int nt = 0; nt < 8; ++nt) {
        int ncol = nt * 128 + wv * 16 + r15;         // this lane's global n-col
        // --- S = Qs.KV^T for the wave's 16-col slab ---
        f32x4 sacc = {};
        if (MODE == 0) {
            const uint4* Bg = (const uint4*)kvbf + ((size_t)(b << 10) + ncol) * 16;
            uint4 b0 = Bg[g], b1 = Bg[4 + g], b2 = Bg[8 + g], b3 = Bg[12 + g];
            uint4 a0 = Al[r15 * 16 + ((0 + g) ^ (r15 & 7))];
            uint4 a1 = Al[r15 * 16 + ((4 + g) ^ (r15 & 7))];
            uint4 a2 = Al[r15 * 16 + ((8 + g) ^ (r15 & 7))];
            uint4 a3 = Al[r15 * 16 + ((12 + g) ^ (r15 & 7))];
            sacc = __builtin_amdgcn_mfma_f32_16x16x32_bf16(
                __builtin_bit_cast(short8, a0), __builtin_bit_cast(short8, b0), sacc, 0, 0, 0);
            sacc = __builtin_amdgcn_mfma_f32_16x16x32_bf16(
                __builtin_bit_cast(short8, a1), __builtin_bit_cast(short8, b1), sacc, 0, 0, 0);
            sacc = __builtin_amdgcn_mfma_f32_16x16x32_bf16(
                __builtin_bit_cast(short8, a2), __builtin_bit_cast(short8, b2), sacc, 0, 0, 0);
            sacc = __builtin_amdgcn_mfma_f32_16x16x32_bf16(
                __builtin_bit_cast(short8, a3), __builtin_bit_cast(short8, b3), sacc, 0, 0, 0);
        }
        // --- epilogue: mask + leaky + exp2 -> P (bf16) + denom ---
        u64 wrdT = 0;
        if (TM) wrdT = bits[((size_t)(b << 10) + ncol) * NW + (mt >> 2)];
        int colt = wv * 16 + r15;                    // col within tile
#pragma unroll
        for (int reg = 0; reg < 4; ++reg) {
            int row_l = g * 4 + reg;                 // C/D: row=(lane>>4)*4+reg
            float ww;
            if (MODE == 1) {
                u64 wrd = bits[((size_t)(b << 10) + mt * 16 + row_l) * NW + (ncol >> 6)];
                ww = (float)((wrd >> (ncol & 63)) & 1);
            } else {
                float p = sacc[reg] + wb;
                p = p >= 0.f ? p : 0.2f * p;         // LeakyReLU(0.2)
                u64 wrd = TM ? wrdT
                             : bits[((size_t)(b << 10) + mt * 16 + row_l) * NW + (ncol >> 6)];
                int bit = TM ? ((mt * 16 + row_l) & 63) : (ncol & 63);
                ww = ((wrd >> bit) & 1) ? exp2f(p) : 0.f;
            }
            u16 h = f2bf(ww);
            dsum[reg] += bf2f(h);                    // match numerator rounding
            ((u16*)Pl)[(row_l * 16 + ((colt >> 3) ^ (row_l & 7))) * 8 + (colt & 7)] = h;
        }
        __syncthreads();
        // --- O += P.VT^T for the wave's 16 d-cols (VT frags from global) ---
        {
            const uint4* Vg = (const uint4*)vt +
                ((size_t)b * H_ + wv * 16 + r15) * 128 + nt * 16;
            uint4 v0 = Vg[g], v1 = Vg[4 + g], v2 = Vg[8 + g], v3 = Vg[12 + g];
            uint4 p0 = Pl[r15 * 16 + ((0 + g) ^ (r15 & 7))];
            uint4 p1 = Pl[r15 * 16 + ((4 + g) ^ (r15 & 7))];
            uint4 p2 = Pl[r15 * 16 + ((8 + g) ^ (r15 & 7))];
            uint4 p3 = Pl[r15 * 16 + ((12 + g) ^ (r15 & 7))];
            oacc = __builtin_amdgcn_mfma_f32_16x16x32_bf16(
                __builtin_bit_cast(short8, p0), __builtin_bit_cast(short8, v0), oacc, 0, 0, 0);
            oacc = __builtin_amdgcn_mfma_f32_16x16x32_bf16(
                __builtin_bit_cast(short8, p1), __builtin_bit_cast(short8, v1), oacc, 0, 0, 0);
            oacc = __builtin_amdgcn_mfma_f32_16x16x32_bf16(
                __builtin_bit_cast(short8, p2), __builtin_bit_cast(short8, v2), oacc, 0, 0, 0);
            oacc = __builtin_amdgcn_mfma_f32_16x16x32_bf16(
                __builtin_bit_cast(short8, p3), __builtin_bit_cast(short8, v3), oacc, 0, 0, 0);
        }
        __syncthreads();
    }

    // --- denominators: reduce over the wave's 16 cols, publish per wave ---
#pragma unroll
    for (int reg = 0; reg < 4; ++reg) {
        float v = dsum[reg];
        v += __shfl_xor(v, 1); v += __shfl_xor(v, 2);
        v += __shfl_xor(v, 4); v += __shfl_xor(v, 8);
        dsum[reg] = v;
    }
    if (r15 == 0)
#pragma unroll
        for (int reg = 0; reg < 4; ++reg)
            dLds[wv * 16 + g * 4 + reg] = dsum[reg];
    __syncthreads();

    // --- normalize + store ---
    int d = wv * 16 + r15;
    u16 hv[4];
#pragma unroll
    for (int reg = 0; reg < 4; ++reg) {
        int row_l = g * 4 + reg;
        float den = 0.f;
#pragma unroll
        for (int w8 = 0; w8 < 8; ++w8) den += dLds[w8 * 16 + row_l];
        float rden = den > 0.f ? 1.0f / den : 0.f;
        float val = oacc[reg] * rden;
        size_t R = (size_t)(b << 10) + mt * 16 + row_l;
        outf[R * H_ + d] = val;
        u16 h = f2bf(val);
        hv[reg] = h;
        if (aux) bfo[R * H_ + d] = h;
    }
    if (aux) {
        // VT-layout copy: rows g*4+reg are consecutive m -> one ushort4
        ushort4 o; o.x = hv[0]; o.y = hv[1]; o.z = hv[2]; o.w = hv[3];
        ((ushort4*)vto)[((size_t)b * H_ + d) * 256 + mt * 4 + g] = o;
    }
}

extern "C" void kernel_launch(void* const* d_in, const int* in_sizes, int n_in,
                              void* d_out, int out_size, void* d_ws, size_t ws_size,
                              hipStream_t stream) {
    const float* nodes_in = (const float*)d_in[0];   // (B,N,H) f32
    const float* adj      = (const float*)d_in[1];   // (B,E,N) f32, binary
    const float* w1       = (const float*)d_in[2];   // (H+1)
    const float* w2       = (const float*)d_in[3];   // (H+1)

    char* ws = (char*)d_ws;
    size_t off = 0;
    u64* bits     = (u64*)(ws + off); off += (size_t)B_ * NROW * NW * sizeof(u64);   // 2 MB
    u16* nodes_bf = (u16*)(ws + off); off += (size_t)B_ * NROW * H_ * sizeof(u16);   // 4 MB
    u16* edge_bf  = (u16*)(ws + off); off += (size_t)B_ * NROW * H_ * sizeof(u16);   // 4 MB
    u16* VTn      = (u16*)(ws + off); off += (size_t)B_ * H_ * NROW * sizeof(u16);   // 4 MB
    u16* VTe      = (u16*)(ws + off); off += (size_t)B_ * H_ * NROW * sizeof(u16);   // 4 MB
    u16* qs       = (u16*)(ws + off); off += (size_t)B_ * NROW * H_ * sizeof(u16);   // 4 MB

    float* out_nodes = (float*)d_out;                        // (B,N,H)
    float* out_edge  = out_nodes + (size_t)B_ * NROW * H_;   // (B,E,H)

    adj_to_bits<<<dim3(B_ * NROW), dim3(256), 0, stream>>>(adj, bits);
    to_bf16    <<<dim3(B_ * NROW * H_ / 1024), dim3(256), 0, stream>>>(nodes_in, nodes_bf);
    trans_vt   <<<dim3(B_ * H_), dim3(256), 0, stream>>>(nodes_in, VTn);
    // edge_init: mean of incident node rows (MODE=1: P = adjacency bits)
    fused_attn <<<dim3(1024), dim3(512), 0, stream>>>(
        nodes_bf, nodes_bf, VTn, bits, w1, out_edge, edge_bf, VTe, 0, 1, 1);

    const float* ncur = nodes_in;
    for (int s = 0; s < 2; ++s) {
        // alpha: q=edge, kv=nodes, mask=adj  -> new edge (+bf16 +VTe)
        prep_q    <<<dim3(2048), dim3(256), 0, stream>>>(out_edge, w1, qs);
        fused_attn<<<dim3(1024), dim3(512), 0, stream>>>(
            qs, nodes_bf, VTn, bits, w1, out_edge, edge_bf, VTe, 0, 0, 1);
        // beta: q=nodes, kv=edge, mask=adj^T -> new nodes (+bf16 +VTn unless last)
        prep_q    <<<dim3(2048), dim3(256), 0, stream>>>(ncur, w2, qs);
        fused_attn<<<dim3(1024), dim3(512), 0, stream>>>(
            qs, edge_bf, VTe, bits, w2, out_nodes, nodes_bf, VTn, 1, 0, s == 0 ? 1 : 0);
        ncur = out_nodes;
    }
}

// Round 16
// 304.686 us; speedup vs baseline: 1.3944x; 1.3944x over previous
//
#include <hip/hip_runtime.h>
#include <cstdint>
#include <cstddef>

#define B_ 16
#define NROW 1024      // E == N == 1024
#define H_ 128
#define NW 16          // u64 words per 1024-bit adjacency row
#define BM 32          // output rows per block

typedef unsigned short u16;
typedef unsigned long long u64;
typedef __attribute__((ext_vector_type(8))) short short8;   // 8 bf16 (4 VGPRs)
typedef __attribute__((ext_vector_type(4))) float f32x4;    // MFMA C/D

__device__ __forceinline__ u16 f2bf(float f) {   // RTNE float->bf16
    unsigned u = __float_as_uint(f);
    return (u16)((u + 0x7fffu + ((u >> 16) & 1u)) >> 16);
}
__device__ __forceinline__ float bf2f(u16 h) {
    return __uint_as_float((unsigned)h << 16);
}

// --- adj (B,E,N) f32 -> bit matrix (B*E rows x 16 u64 words) ---
__global__ void adj_to_bits(const float* __restrict__ adj, u64* __restrict__ bits) {
    int be = blockIdx.x;                      // 16384
    const float* row = adj + (size_t)be * NROW;
    int tid = threadIdx.x, lane = tid & 63, wv = tid >> 6;
    for (int c0 = 0; c0 < NROW; c0 += 256) {
        float v = row[c0 + tid];
        u64 m = __ballot(v != 0.0f);
        if (lane == 0) bits[(size_t)be * NW + (c0 >> 6) + wv] = m;
    }
}

// --- fp32 -> bf16 copy (row-major), 4 elems/thread ---
__global__ void to_bf16(const float* __restrict__ in, u16* __restrict__ out) {
    int i = blockIdx.x * 256 + threadIdx.x;
    float4 v = ((const float4*)in)[i];
    ushort4 r;
    r.x = f2bf(v.x); r.y = f2bf(v.y); r.z = f2bf(v.z); r.w = f2bf(v.w);
    ((ushort4*)out)[i] = r;
}

// --- vt[b][d][n] = bf16(src[b][n][d]), d<128 ---
__global__ void trans_vt(const float* __restrict__ src, u16* __restrict__ vt) {
    int blk = blockIdx.x;                 // B_*128
    int b = blk >> 7, d = blk & 127;
    int t = threadIdx.x;                  // 256 threads x 4 n each
    const float* sp = src + ((size_t)b << 10) * H_ + d;
    ushort4 o;
    o.x = f2bf(sp[(size_t)(t * 4 + 0) * H_]);
    o.y = f2bf(sp[(size_t)(t * 4 + 1) * H_]);
    o.z = f2bf(sp[(size_t)(t * 4 + 2) * H_]);
    o.w = f2bf(sp[(size_t)(t * 4 + 3) * H_]);
    ((ushort4*)(vt + ((size_t)b * H_ + d) * NROW))[t] = o;
}

// --- qs[b][r][k] = bf16(src[b][r][k] * w[k] * log2e) ---
__global__ void prep_q(const float* __restrict__ src, const float* __restrict__ w,
                       u16* __restrict__ qs) {
    int idx = blockIdx.x * 256 + threadIdx.x;   // float4 index
    float4 v = ((const float4*)src)[idx];
    float4 wv = ((const float4*)w)[idx & 31];
    const float L2E = 1.44269504f;
    ushort4 r;
    r.x = f2bf(v.x * wv.x * L2E);
    r.y = f2bf(v.y * wv.y * L2E);
    r.z = f2bf(v.z * wv.z * L2E);
    r.w = f2bf(v.w * wv.w * L2E);
    ((ushort4*)qs)[idx] = r;
}

// --- Fused flash attention phase, BM=32, dbuf P, B-operands from global ---
// Grid 512 = 16 b x 32 mt (2 blocks/CU); 512 thr = 8 waves; LDS 25 KB.
// B-ops direct from global (r15-validated: each KV/VT element feeds exactly
// one wave). Only Al (reused 8x) and double-buffered Pl (cross-wave) in LDS.
// Per nt: S = Qs.KV^T (8 MFMA) -> mask/leaky/exp2 -> P bf16 to Pl[nt&1]
// (+ bf16-rounded fp32 denom) -> ONE barrier -> O += P.VT^T (8 MFMA).
// MODE=1 (edge_init): P = mask bits as {0,1} (skips Qs/KV/S).
// TM=0: mask=bits[m-row][n-col] (alpha). TM=1: mask=bits[n-col][m-row] (beta).
// aux=1: bf16 row-major copy + LDS-transposed coalesced VT-layout copy (r14
// pattern; r15's strided direct write caused 3x RMW write amplification).
__global__ void __launch_bounds__(512, 4)
fused_attn(const u16* __restrict__ qs, const u16* __restrict__ kvbf,
           const u16* __restrict__ vt, const u64* __restrict__ bits,
           const float* __restrict__ w,
           float* __restrict__ outf, u16* __restrict__ bfo, u16* __restrict__ vto,
           int TM, int MODE, int aux) {
    __shared__ uint4 Al[BM * 16];        // 8 KB  q tile [32 m][128 k]
    __shared__ uint4 Pl[2][BM * 16];     // 16 KB P tile double buffer
    __shared__ float dLds[8 * BM];       // 1 KB  per-wave row denominators

    int x = blockIdx.x;                  // 512
    int xcd = x & 7;
    int j = x >> 3;                      // 0..63
    int b = xcd + ((j >> 5) << 3);       // batches {xcd, xcd+8} on XCD xcd
    int mt = j & 31;
    int t = threadIdx.x;
    int lane = t & 63, wv = t >> 6;      // 8 waves
    int r15 = lane & 15, g = lane >> 4;

    if (MODE == 0) {                     // stage q tile: 512 chunks = 512 thr
        int row = t >> 4, kc = t & 15;
        Al[row * 16 + (kc ^ (row & 7))] =
            ((const uint4*)qs)[((size_t)(b << 10) + mt * BM + row) * 16 + kc];
    }
    float wb = (MODE == 0) ? w[H_] * 1.44269504f : 0.f;
    f32x4 oacc[2] = {};
    float dsum[2][4] = {};
    __syncthreads();

    for (int nt = 0; nt < 8; ++nt) {
        int ncol = nt * 128 + wv * 16 + r15;      // this lane's global n-col
        // --- S = Qs.KV^T for the wave's 16-col slab (B frags from global) ---
        f32x4 sacc[2] = {};
        if (MODE == 0) {
            const uint4* Bg = (const uint4*)kvbf + ((size_t)(b << 10) + ncol) * 16;
            uint4 b0 = Bg[g], b1 = Bg[4 + g], b2 = Bg[8 + g], b3 = Bg[12 + g];
#pragma unroll
            for (int mi = 0; mi < 2; ++mi) {
                int ar = mi * 16 + r15;
                uint4 a0 = Al[ar * 16 + ((0 + g) ^ (r15 & 7))];
                uint4 a1 = Al[ar * 16 + ((4 + g) ^ (r15 & 7))];
                uint4 a2 = Al[ar * 16 + ((8 + g) ^ (r15 & 7))];
                uint4 a3 = Al[ar * 16 + ((12 + g) ^ (r15 & 7))];
                sacc[mi] = __builtin_amdgcn_mfma_f32_16x16x32_bf16(
                    __builtin_bit_cast(short8, a0), __builtin_bit_cast(short8, b0), sacc[mi], 0, 0, 0);
                sacc[mi] = __builtin_amdgcn_mfma_f32_16x16x32_bf16(
                    __builtin_bit_cast(short8, a1), __builtin_bit_cast(short8, b1), sacc[mi], 0, 0, 0);
                sacc[mi] = __builtin_amdgcn_mfma_f32_16x16x32_bf16(
                    __builtin_bit_cast(short8, a2), __builtin_bit_cast(short8, b2), sacc[mi], 0, 0, 0);
                sacc[mi] = __builtin_amdgcn_mfma_f32_16x16x32_bf16(
                    __builtin_bit_cast(short8, a3), __builtin_bit_cast(short8, b3), sacc[mi], 0, 0, 0);
            }
        }
        // --- epilogue: mask + leaky + exp2 -> P bf16 + denom ---
        u64 wrdT = 0;
        if (TM && MODE == 0)
            wrdT = bits[((size_t)(b << 10) + ncol) * NW + (mt >> 1)];
        int colt = wv * 16 + r15;
        u16* Pb = (u16*)Pl[nt & 1];
#pragma unroll
        for (int mi = 0; mi < 2; ++mi) {
#pragma unroll
            for (int reg = 0; reg < 4; ++reg) {
                int row_l = mi * 16 + g * 4 + reg;    // C/D: row=(lane>>4)*4+reg
                float ww;
                if (MODE == 1) {
                    u64 wrd = bits[((size_t)(b << 10) + mt * BM + row_l) * NW + (ncol >> 6)];
                    ww = (float)((wrd >> (ncol & 63)) & 1);
                } else {
                    float p = sacc[mi][reg] + wb;
                    p = p >= 0.f ? p : 0.2f * p;      // LeakyReLU(0.2)
                    u64 wrd = TM ? wrdT
                                 : bits[((size_t)(b << 10) + mt * BM + row_l) * NW + (ncol >> 6)];
                    int bit = TM ? ((mt & 1) * 32 + row_l) : (ncol & 63);
                    ww = ((wrd >> bit) & 1) ? exp2f(p) : 0.f;
                }
                u16 h = f2bf(ww);
                dsum[mi][reg] += bf2f(h);             // match numerator rounding
                Pb[(row_l * 16 + ((colt >> 3) ^ (row_l & 7))) * 8 + (colt & 7)] = h;
            }
        }
        __syncthreads();   // P(nt) ready; dbuf makes this the ONLY barrier/iter
        // --- O += P.VT^T for the wave's 16 d-cols (VT frags from global) ---
        {
            const uint4* Vg = (const uint4*)vt +
                ((size_t)b * H_ + wv * 16 + r15) * 128 + nt * 16;
            uint4 v0 = Vg[g], v1 = Vg[4 + g], v2 = Vg[8 + g], v3 = Vg[12 + g];
            const uint4* Pb4 = Pl[nt & 1];
#pragma unroll
            for (int mi = 0; mi < 2; ++mi) {
                int pr = mi * 16 + r15;
                uint4 p0 = Pb4[pr * 16 + ((0 + g) ^ (r15 & 7))];
                uint4 p1 = Pb4[pr * 16 + ((4 + g) ^ (r15 & 7))];
                uint4 p2 = Pb4[pr * 16 + ((8 + g) ^ (r15 & 7))];
                uint4 p3 = Pb4[pr * 16 + ((12 + g) ^ (r15 & 7))];
                oacc[mi] = __builtin_amdgcn_mfma_f32_16x16x32_bf16(
                    __builtin_bit_cast(short8, p0), __builtin_bit_cast(short8, v0), oacc[mi], 0, 0, 0);
                oacc[mi] = __builtin_amdgcn_mfma_f32_16x16x32_bf16(
                    __builtin_bit_cast(short8, p1), __builtin_bit_cast(short8, v1), oacc[mi], 0, 0, 0);
                oacc[mi] = __builtin_amdgcn_mfma_f32_16x16x32_bf16(
                    __builtin_bit_cast(short8, p2), __builtin_bit_cast(short8, v2), oacc[mi], 0, 0, 0);
                oacc[mi] = __builtin_amdgcn_mfma_f32_16x16x32_bf16(
                    __builtin_bit_cast(short8, p3), __builtin_bit_cast(short8, v3), oacc[mi], 0, 0, 0);
            }
        }
    }

    // --- denominators: reduce over the wave's 16 cols, publish per wave ---
#pragma unroll
    for (int mi = 0; mi < 2; ++mi)
#pragma unroll
        for (int reg = 0; reg < 4; ++reg) {
            float v = dsum[mi][reg];
            v += __shfl_xor(v, 1); v += __shfl_xor(v, 2);
            v += __shfl_xor(v, 4); v += __shfl_xor(v, 8);
            dsum[mi][reg] = v;
        }
    if (r15 == 0)
#pragma unroll
        for (int mi = 0; mi < 2; ++mi)
#pragma unroll
            for (int reg = 0; reg < 4; ++reg)
                dLds[wv * BM + mi * 16 + g * 4 + reg] = dsum[mi][reg];
    __syncthreads();

    // --- normalize + store fp32/bf16; stash bf16 tile in Pl[0] for vto ---
    int d = wv * 16 + r15;
    u16* Ob = (u16*)Pl[0];
#pragma unroll
    for (int mi = 0; mi < 2; ++mi) {
#pragma unroll
        for (int reg = 0; reg < 4; ++reg) {
            int row_l = mi * 16 + g * 4 + reg;
            float den = 0.f;
#pragma unroll
            for (int w8 = 0; w8 < 8; ++w8) den += dLds[w8 * BM + row_l];
            float rden = den > 0.f ? 1.0f / den : 0.f;
            float val = oacc[mi][reg] * rden;
            size_t R = (size_t)(b << 10) + mt * BM + row_l;
            outf[R * H_ + d] = val;
            u16 h = f2bf(val);
            if (aux) bfo[R * H_ + d] = h;
            Ob[(row_l * 16 + ((d >> 3) ^ (row_l & 7))) * 8 + (d & 7)] = h;
        }
    }
    if (aux) {
        __syncthreads();
        // coalesced VT write: thread t -> (d = t>>2, m-chunk mc = t&3)
        int dd = t >> 2, mc = t & 3;
        u16 tmp[8];
#pragma unroll
        for (int j2 = 0; j2 < 8; ++j2) {
            int m = mc * 8 + j2;
            tmp[j2] = Ob[(m * 16 + ((dd >> 3) ^ (m & 7))) * 8 + (dd & 7)];
        }
        uint4 o;
        o.x = (unsigned)tmp[0] | ((unsigned)tmp[1] << 16);
        o.y = (unsigned)tmp[2] | ((unsigned)tmp[3] << 16);
        o.z = (unsigned)tmp[4] | ((unsigned)tmp[5] << 16);
        o.w = (unsigned)tmp[6] | ((unsigned)tmp[7] << 16);
        ((uint4*)vto)[((size_t)b * H_ + dd) * 128 + mt * 4 + mc] = o;
    }
}

extern "C" void kernel_launch(void* const* d_in, const int* in_sizes, int n_in,
                              void* d_out, int out_size, void* d_ws, size_t ws_size,
                              hipStream_t stream) {
    const float* nodes_in = (const float*)d_in[0];   // (B,N,H) f32
    const float* adj      = (const float*)d_in[1];   // (B,E,N) f32, binary
    const float* w1       = (const float*)d_in[2];   // (H+1)
    const float* w2       = (const float*)d_in[3];   // (H+1)

    char* ws = (char*)d_ws;
    size_t off = 0;
    u64* bits     = (u64*)(ws + off); off += (size_t)B_ * NROW * NW * sizeof(u64);   // 2 MB
    u16* nodes_bf = (u16*)(ws + off); off += (size_t)B_ * NROW * H_ * sizeof(u16);   // 4 MB
    u16* edge_bf  = (u16*)(ws + off); off += (size_t)B_ * NROW * H_ * sizeof(u16);   // 4 MB
    u16* VTn      = (u16*)(ws + off); off += (size_t)B_ * H_ * NROW * sizeof(u16);   // 4 MB
    u16* VTe      = (u16*)(ws + off); off += (size_t)B_ * H_ * NROW * sizeof(u16);   // 4 MB
    u16* qs       = (u16*)(ws + off); off += (size_t)B_ * NROW * H_ * sizeof(u16);   // 4 MB

    float* out_nodes = (float*)d_out;                        // (B,N,H)
    float* out_edge  = out_nodes + (size_t)B_ * NROW * H_;   // (B,E,H)

    adj_to_bits<<<dim3(B_ * NROW), dim3(256), 0, stream>>>(adj, bits);
    to_bf16    <<<dim3(B_ * NROW * H_ / 1024), dim3(256), 0, stream>>>(nodes_in, nodes_bf);
    trans_vt   <<<dim3(B_ * H_), dim3(256), 0, stream>>>(nodes_in, VTn);
    // edge_init: mean of incident node rows (MODE=1: P = adjacency bits)
    fused_attn <<<dim3(512), dim3(512), 0, stream>>>(
        nodes_bf, nodes_bf, VTn, bits, w1, out_edge, edge_bf, VTe, 0, 1, 1);

    const float* ncur = nodes_in;
    for (int s = 0; s < 2; ++s) {
        // alpha: q=edge, kv=nodes, mask=adj  -> new edge (+bf16 +VTe)
        prep_q    <<<dim3(2048), dim3(256), 0, stream>>>(out_edge, w1, qs);
        fused_attn<<<dim3(512), dim3(512), 0, stream>>>(
            qs, nodes_bf, VTn, bits, w1, out_edge, edge_bf, VTe, 0, 0, 1);
        // beta: q=nodes, kv=edge, mask=adj^T -> new nodes (+bf16 +VTn unless last)
        prep_q    <<<dim3(2048), dim3(256), 0, stream>>>(ncur, w2, qs);
        fused_attn<<<dim3(512), dim3(512), 0, stream>>>(
            qs, edge_bf, VTe, bits, w2, out_nodes, nodes_bf, VTn, 1, 0, s == 0 ? 1 : 0);
        ncur = out_nodes;
    }
}